// Round 11
// baseline (174.814 us; speedup 1.0000x reference)
//
#include <hip/hip_runtime.h>

// ScaledDotProductAttention: causal cosine attention.
// B=4 H=16 N=2048 D=64, fp32 in/out, bf16 MFMA compute.
//
// Round 11: 64 q-rows per wave (two 32-row sets share one K/V fragment
// read -> LDS read traffic halves: 1.08 GB -> 540 MB; r10's wall was the
// SUM of LDS+MFMA+VALU pipe time under phase-lockstep). 4 waves x 64 rows
// = QBLK 256. Paired grid: block i and i+256 (co-resident) have qb summing
// to 7 -> every CU gets exactly 36 block-iters. Triple-buffered stage,
// counted vmcnt (8/4/0), raw s_barriers.
//  - Kn/Vt pre-swizzled (elem ^= (row&7)<<3 per 64x64 tile), gload_lds(16B).
//  - no-max softmax: scores cosine-bounded (|s| <= g*log2e ~31.7), so
//    p = exp2(s) directly -- exact by shift-invariance.
//  - swapped-operand MFMA, cvt_pk + permlane32_swap P repack.

#define BATCH 4
#define HEADS 16
#define SEQ   2048
#define DIM   64
#define EPS   1e-8f
#define LOG2E 1.44269504088896340736f

typedef short bf16x8 __attribute__((ext_vector_type(8)));
typedef short s16x4  __attribute__((ext_vector_type(4)));
typedef float fx16   __attribute__((ext_vector_type(16)));
typedef unsigned int u32x4 __attribute__((ext_vector_type(4)));

static __device__ __forceinline__ short f2bf(float x) {
    unsigned u = __float_as_uint(x);
    unsigned r = (u + 0x7fffu + ((u >> 16) & 1u)) >> 16;   // RNE
    return (short)r;
}
static __device__ __forceinline__ unsigned cvt_pk(float lo, float hi) {
    unsigned r;
    asm("v_cvt_pk_bf16_f32 %0, %1, %2" : "=v"(r) : "v"(lo), "v"(hi));
    return r;
}
static __device__ __forceinline__ void gload_lds16(const short* g, short* l) {
    __builtin_amdgcn_global_load_lds(
        (const __attribute__((address_space(1))) void*)g,
        (__attribute__((address_space(3))) void*)l, 16, 0, 0);
}

// ---------------------------------------------------------------------------
// Kernel 1: K rows -> L2-normalized bf16, tiled+swizzled layout:
// Kn[bh][kt][r][e ^ ((r&7)<<3)] = Khat[bh][kt*64+r][e]
// ---------------------------------------------------------------------------
__global__ __launch_bounds__(256) void norm_k(
    const float* __restrict__ K, short* __restrict__ Kn)
{
    const int tid  = threadIdx.x;
    const int lane = tid & 63;
    long long rid = (long long)blockIdx.x * 16 + (tid >> 6) * 4 + (lane >> 4);
    const int c4 = (lane & 15) * 4;

    const float* src = K + rid * DIM;
    float4 v = *(const float4*)(src + c4);
    float ss = v.x * v.x + v.y * v.y + v.z * v.z + v.w * v.w;
    ss += __shfl_xor(ss, 1);
    ss += __shfl_xor(ss, 2);
    ss += __shfl_xor(ss, 4);
    ss += __shfl_xor(ss, 8);
    float s = 1.0f / (sqrtf(ss) + EPS);

    const int bh = (int)(rid >> 11);
    const int n  = (int)(rid & 2047);
    const int kt = n >> 6;
    const int r  = n & 63;
    short* dst = Kn + ((size_t)bh << 17) + (kt << 12) + (r << 6);

    s16x4 o;
    o[0] = f2bf(v.x * s);
    o[1] = f2bf(v.y * s);
    o[2] = f2bf(v.z * s);
    o[3] = f2bf(v.w * s);
    *(s16x4*)(dst + (c4 ^ ((r & 7) << 3))) = o;
}

// ---------------------------------------------------------------------------
// Kernel 2: V [n][d] fp32 -> Vt tiled+swizzled bf16:
// Vt[bh][kt][d][k ^ ((d&7)<<3)] = V[bh][kt*64+k][d]
// ---------------------------------------------------------------------------
#define TLDS 68

__global__ __launch_bounds__(256) void transpose_v(
    const float* __restrict__ V, short* __restrict__ Vt)
{
    const int nt = blockIdx.x;
    const int bh = blockIdx.y;
    const float* Vb = V + ((size_t)bh * SEQ + (size_t)nt * 64) * DIM;
    short* Vo = Vt + ((size_t)bh << 17) + (nt << 12);

    __shared__ short lds[DIM * TLDS];
    const int t  = threadIdx.x;
    const int cg = t & 15;
    const int rr = t >> 4;

#pragma unroll
    for (int i = 0; i < 4; ++i) {
        int n  = rr + i * 16;
        int d0 = cg * 4;
        float4 v = *(const float4*)(Vb + (size_t)n * DIM + d0);
        lds[(d0 + 0) * TLDS + n] = f2bf(v.x);
        lds[(d0 + 1) * TLDS + n] = f2bf(v.y);
        lds[(d0 + 2) * TLDS + n] = f2bf(v.z);
        lds[(d0 + 3) * TLDS + n] = f2bf(v.w);
    }
    __syncthreads();
#pragma unroll
    for (int i = 0; i < 4; ++i) {
        int d  = rr + i * 16;
        int nl = cg * 4;
        s16x4 o;
        o[0] = lds[d * TLDS + nl + 0];
        o[1] = lds[d * TLDS + nl + 1];
        o[2] = lds[d * TLDS + nl + 2];
        o[3] = lds[d * TLDS + nl + 3];
        *(s16x4*)(Vo + (d << 6) + (nl ^ ((d & 7) << 3))) = o;
    }
}

// ---------------------------------------------------------------------------
// Per-q-set body: QK^T -> no-max softmax -> repack -> PV accumulate.
// ---------------------------------------------------------------------------
static __device__ __forceinline__ void attn_set(
    const bf16x8 (&kf)[2][4], const bf16x8 (&vf)[2][4],
    const bf16x8 (&qbf)[4], int k0, int wloS, int qrowS, int hi,
    fx16 (&oacc)[2], float &lsum)
{
    fx16 sacc[2];
#pragma unroll
    for (int t = 0; t < 2; ++t)
#pragma unroll
        for (int r = 0; r < 16; ++r) sacc[t][r] = 0.f;

    __builtin_amdgcn_s_setprio(1);
#pragma unroll
    for (int c = 0; c < 4; ++c) {
        sacc[0] = __builtin_amdgcn_mfma_f32_32x32x16_bf16(kf[0][c], qbf[c], sacc[0], 0, 0, 0);
        sacc[1] = __builtin_amdgcn_mfma_f32_32x32x16_bf16(kf[1][c], qbf[c], sacc[1], 0, 0, 0);
    }
    __builtin_amdgcn_s_setprio(0);

    float p[32];
#pragma unroll
    for (int t = 0; t < 2; ++t)
#pragma unroll
        for (int r = 0; r < 16; ++r) p[t * 16 + r] = sacc[t][r];

    // causal mask: only the tile crossing this set's diagonal
    if (k0 + 63 > wloS) {
#pragma unroll
        for (int t = 0; t < 2; ++t)
#pragma unroll
            for (int r = 0; r < 16; ++r) {
                int key = k0 + 32 * t + (r & 3) + 8 * (r >> 2) + 4 * hi;
                if (key > qrowS) p[t * 16 + r] = -3.0e38f;
            }
    }

    // p = exp2(s): cosine-bounded scores, no max shift needed
#pragma unroll
    for (int r = 0; r < 32; ++r)
        p[r] = __builtin_amdgcn_exp2f(p[r]);

    // lsum += row sum
    float ts[16];
#pragma unroll
    for (int r = 0; r < 16; ++r) ts[r] = p[r] + p[r + 16];
#pragma unroll
    for (int r = 0; r < 8; ++r) ts[r] += ts[r + 8];
#pragma unroll
    for (int r = 0; r < 4; ++r) ts[r] += ts[r + 4];
    float ps = (ts[0] + ts[1]) + (ts[2] + ts[3]);
    ps += __shfl_xor(ps, 32);
    lsum += ps;

    // repack P -> B-fragments via v_permlane32_swap_b32
    u32x4 paw[4];
#pragma unroll
    for (int ks = 0; ks < 4; ++ks) {
        const int t = ks >> 1;
        const int b0 = (ks & 1) * 8;
#pragma unroll
        for (int m = 0; m < 2; ++m) {
            unsigned a = cvt_pk(p[t * 16 + b0 + 2 * m], p[t * 16 + b0 + 2 * m + 1]);
            unsigned b = cvt_pk(p[t * 16 + b0 + 2 * m + 4], p[t * 16 + b0 + 2 * m + 5]);
            asm("v_permlane32_swap_b32 %0, %1" : "+v"(a), "+v"(b));
            paw[ks][m]     = a;
            paw[ks][m + 2] = b;
        }
    }

    // O' += Vt x P
    __builtin_amdgcn_s_setprio(1);
#pragma unroll
    for (int dt = 0; dt < 2; ++dt)
#pragma unroll
        for (int ks = 0; ks < 4; ++ks) {
            bf16x8 pa = __builtin_bit_cast(bf16x8, paw[ks]);
            oacc[dt] = __builtin_amdgcn_mfma_f32_32x32x16_bf16(vf[dt][ks], pa, oacc[dt], 0, 0, 0);
        }
    __builtin_amdgcn_s_setprio(0);
}

// ---------------------------------------------------------------------------
// Kernel 3: flash attention. 256 threads = 4 waves x 64 q-rows (two 32-row
// sets sharing one K/V fragment read). QBLK=256, KVBLK=64, triple-buffered
// stage 2 ahead, counted vmcnt (8/4/0).
//
// mfma_f32_32x32x16_bf16 layouts:
//   A: row = lane&31, k = (lane>>5)*8 + j
//   B: col = lane&31, k = (lane>>5)*8 + j
//   C/D: col = lane&31, row = (reg&3) + 8*(reg>>2) + 4*(lane>>5)
// ---------------------------------------------------------------------------
__global__ __launch_bounds__(256) void attn_fwd(
    const float* __restrict__ Q, const float* __restrict__ scale,
    const short* __restrict__ Kn, const short* __restrict__ Vt,
    float* __restrict__ out)
{
    const int lid = blockIdx.x;                       // 0..511
    // block i and i+256 share a CU slot: qb(i) + qb(i+256) = 7 (36 iters/CU)
    const int qq  = (lid >> 6) & 3;
    const int qb  = (lid < 256) ? (7 - qq) : qq;
    const int bh  = (lid & 7) * 8 + ((lid >> 3) & 7); // XCD lid%8 owns bh/8
    const int tid = threadIdx.x;
    const int w   = tid >> 6;                         // wave 0..3
    const int l   = tid & 63;
    const int lq  = l & 31;
    const int hi  = l >> 5;

    const short* Kb = Kn + ((size_t)bh << 17);
    const short* Vb = Vt + ((size_t)bh << 17);
    const float  g  = scale[bh & (HEADS - 1)];

    __shared__ __align__(16) short ldsK[3][64 * 64];
    __shared__ __align__(16) short ldsV[3][64 * 64];

    const int toff = tid * 8;   // 256 thr x 8 shorts = 2048 shorts per round

    const int wlo   = qb * 256 + w * 64;   // wave's first q-row
    const int qrowA = wlo + lq;
    const int qrowB = wlo + 32 + lq;
    const int nkt   = 4 * qb + 4;

    // ---- Q loads FIRST (oldest in vmcnt queue: their drain won't flush
    //      the stage loads issued below) ----
    const float* QrA = Q + ((size_t)bh * SEQ + qrowA) * DIM;
    const float* QrB = QrA + 32 * DIM;
    float qvA[4][8], qvB[4][8];
#pragma unroll
    for (int c = 0; c < 4; ++c) {
        float4 a0 = *(const float4*)(QrA + c * 16 + hi * 8);
        float4 a1 = *(const float4*)(QrA + c * 16 + hi * 8 + 4);
        float4 b0 = *(const float4*)(QrB + c * 16 + hi * 8);
        float4 b1 = *(const float4*)(QrB + c * 16 + hi * 8 + 4);
        qvA[c][0] = a0.x; qvA[c][1] = a0.y; qvA[c][2] = a0.z; qvA[c][3] = a0.w;
        qvA[c][4] = a1.x; qvA[c][5] = a1.y; qvA[c][6] = a1.z; qvA[c][7] = a1.w;
        qvB[c][0] = b0.x; qvB[c][1] = b0.y; qvB[c][2] = b0.z; qvB[c][3] = b0.w;
        qvB[c][4] = b1.x; qvB[c][5] = b1.y; qvB[c][6] = b1.z; qvB[c][7] = b1.w;
    }

    // ---- prologue: stage tiles 0 and 1 ----
    gload_lds16(Kb + toff,        &ldsK[0][toff]);
    gload_lds16(Kb + 2048 + toff, &ldsK[0][2048 + toff]);
    gload_lds16(Vb + toff,        &ldsV[0][toff]);
    gload_lds16(Vb + 2048 + toff, &ldsV[0][2048 + toff]);
    gload_lds16(Kb + 4096 + toff, &ldsK[1][toff]);
    gload_lds16(Kb + 6144 + toff, &ldsK[1][2048 + toff]);
    gload_lds16(Vb + 4096 + toff, &ldsV[1][toff]);
    gload_lds16(Vb + 6144 + toff, &ldsV[1][2048 + toff]);

    // ---- fused Q-norm for both sets ----
    float ssA = 0.f, ssB = 0.f;
#pragma unroll
    for (int c = 0; c < 4; ++c)
#pragma unroll
        for (int jj = 0; jj < 8; ++jj) {
            ssA += qvA[c][jj] * qvA[c][jj];
            ssB += qvB[c][jj] * qvB[c][jj];
        }
    ssA += __shfl_xor(ssA, 32);
    ssB += __shfl_xor(ssB, 32);
    const float scA = g * LOG2E / (sqrtf(ssA) + EPS);
    const float scB = g * LOG2E / (sqrtf(ssB) + EPS);

    bf16x8 qbfA[4], qbfB[4];
#pragma unroll
    for (int c = 0; c < 4; ++c) {
        u32x4 wa, wb;
#pragma unroll
        for (int m = 0; m < 4; ++m) {
            wa[m] = cvt_pk(qvA[c][2 * m] * scA, qvA[c][2 * m + 1] * scA);
            wb[m] = cvt_pk(qvB[c][2 * m] * scB, qvB[c][2 * m + 1] * scB);
        }
        qbfA[c] = __builtin_bit_cast(bf16x8, wa);
        qbfB[c] = __builtin_bit_cast(bf16x8, wb);
    }

    fx16 oaccA[2], oaccB[2];
#pragma unroll
    for (int dt = 0; dt < 2; ++dt)
#pragma unroll
        for (int r = 0; r < 16; ++r) { oaccA[dt][r] = 0.f; oaccB[dt][r] = 0.f; }
    float lsumA = 0.f, lsumB = 0.f;

    int cur = 0;   // kt % 3
    for (int kt = 0; kt < nkt; ++kt) {
        // bar A: all waves finished compute(kt-1) -> buf[(kt+2)%3] is free
        __builtin_amdgcn_s_barrier();

        if (kt + 2 < nkt) {
            int nb = cur + 2; if (nb >= 3) nb -= 3;
            const short* gK = Kb + (size_t)(kt + 2) * 4096;
            const short* gV = Vb + (size_t)(kt + 2) * 4096;
            gload_lds16(gK + toff,        &ldsK[nb][toff]);
            gload_lds16(gK + 2048 + toff, &ldsK[nb][2048 + toff]);
            gload_lds16(gV + toff,        &ldsV[nb][toff]);
            gload_lds16(gV + 2048 + toff, &ldsV[nb][2048 + toff]);
            // own stage(kt) done; stages (kt+1),(kt+2) = 8 loads in flight
            asm volatile("s_waitcnt vmcnt(8)" ::: "memory");
        } else if (kt + 1 < nkt) {
            asm volatile("s_waitcnt vmcnt(4)" ::: "memory");
        } else {
            asm volatile("s_waitcnt vmcnt(0)" ::: "memory");
        }
        // bar B: all waves' stage(kt) slices visible
        __builtin_amdgcn_s_barrier();

        const int k0 = kt * 64;
        if (k0 <= wlo) {   // wave-uniform causal skip (barriers outside)
            const short* lk = ldsK[cur];
            const short* lv = ldsV[cur];

            bf16x8 kf[2][4], vf[2][4];
#pragma unroll
            for (int t = 0; t < 2; ++t)
#pragma unroll
                for (int c = 0; c < 4; ++c) {
                    int r = t * 32 + lq;
                    kf[t][c] = *(const bf16x8*)
                        &lk[(r << 6) + ((c * 16 + hi * 8) ^ ((r & 7) << 3))];
                }
#pragma unroll
            for (int dt = 0; dt < 2; ++dt)
#pragma unroll
                for (int ks = 0; ks < 4; ++ks) {
                    int d = dt * 32 + lq;
                    vf[dt][ks] = *(const bf16x8*)
                        &lv[(d << 6) + ((ks * 16 + hi * 8) ^ ((d & 7) << 3))];
                }

            attn_set(kf, vf, qbfA, k0, wlo,      qrowA, hi, oaccA, lsumA);
            attn_set(kf, vf, qbfB, k0, wlo + 32, qrowB, hi, oaccB, lsumB);
        }
        cur = (cur == 2) ? 0 : cur + 1;
    }

    // ---- epilogue: out[q][d] = O'/lsum for both sets ----
    const float invA = 1.0f / lsumA;
    const float invB = 1.0f / lsumB;
    size_t rbA = ((size_t)bh * SEQ + (size_t)qrowA) * DIM;
    size_t rbB = rbA + (size_t)32 * DIM;
#pragma unroll
    for (int dt = 0; dt < 2; ++dt)
#pragma unroll
        for (int g4 = 0; g4 < 4; ++g4) {
            float4 oA, oB;
            oA.x = oaccA[dt][4 * g4 + 0] * invA;
            oA.y = oaccA[dt][4 * g4 + 1] * invA;
            oA.z = oaccA[dt][4 * g4 + 2] * invA;
            oA.w = oaccA[dt][4 * g4 + 3] * invA;
            oB.x = oaccB[dt][4 * g4 + 0] * invB;
            oB.y = oaccB[dt][4 * g4 + 1] * invB;
            oB.z = oaccB[dt][4 * g4 + 2] * invB;
            oB.w = oaccB[dt][4 * g4 + 3] * invB;
            *(float4*)(out + rbA + dt * 32 + 8 * g4 + 4 * hi) = oA;
            *(float4*)(out + rbB + dt * 32 + 8 * g4 + 4 * hi) = oB;
        }
}

// ---------------------------------------------------------------------------
extern "C" void kernel_launch(void* const* d_in, const int* in_sizes, int n_in,
                              void* d_out, int out_size, void* d_ws, size_t ws_size,
                              hipStream_t stream)
{
    const float* Q  = (const float*)d_in[0];
    const float* K  = (const float*)d_in[1];
    const float* V  = (const float*)d_in[2];
    const float* qs = (const float*)d_in[3];
    float* out = (float*)d_out;

    const size_t nElem = (size_t)BATCH * HEADS * SEQ * DIM;
    short* Kn = (short*)d_ws;
    short* Vt = Kn + nElem;

    {
        long long rows = (long long)BATCH * HEADS * SEQ;
        norm_k<<<(int)(rows / 16), 256, 0, stream>>>(K, Kn);
    }
    {
        dim3 grid(SEQ / 64, BATCH * HEADS);
        transpose_v<<<grid, 256, 0, stream>>>(V, Vt);
    }
    {
        // 512 blocks = 2/CU; co-resident pair sums to uniform 36 iters
        attn_fwd<<<(SEQ / 256) * BATCH * HEADS * 2, 256, 0, stream>>>(Q, qs, Kn, Vt, out);
    }
}

// Round 12
// 76.144 us; speedup vs baseline: 2.2959x; 2.2959x over previous
//
#include <hip/hip_runtime.h>

// ScaledDotProductAttention: causal cosine attention.
// B=4 H=16 N=2048 D=64, fp32 in/out, bf16 MFMA compute.
//
// Round 12: r10 inner body (VGPR ~76, best known) with two fixes:
//  (1) balanced co-residency: qb = (lid<256)? 7-(lid>>6) : (lid>>6)-4 ->
//      the two blocks sharing a CU always sum to qb=7 -> every CU runs
//      exactly 18 rounds (r10's mapping gave 12..24: +33% tail on worst CU).
//  (2) KVBLK=128 rounds: stage two 64-tiles per barrier round (dbuf 32 KB
//      buffers, 64 KB LDS, 2 blocks/CU), compute sub-tiles back-to-back ->
//      half the barriers per key, two independent chains for the scheduler.
//  - QBLK=256 (8 waves x 32 q-rows), counted vmcnt (4/0), raw s_barriers.
//  - Kn/Vt pre-swizzled (elem ^= (row&7)<<3 per 64x64 tile), gload_lds(16B).
//  - no-max softmax: scores cosine-bounded (|s| <= g*log2e ~31.7), so
//    p = exp2(s) directly -- exact by shift-invariance.
//  - swapped-operand MFMA, cvt_pk + permlane32_swap P repack.

#define BATCH 4
#define HEADS 16
#define SEQ   2048
#define DIM   64
#define EPS   1e-8f
#define LOG2E 1.44269504088896340736f

typedef short bf16x8 __attribute__((ext_vector_type(8)));
typedef short s16x4  __attribute__((ext_vector_type(4)));
typedef float fx16   __attribute__((ext_vector_type(16)));
typedef unsigned int u32x4 __attribute__((ext_vector_type(4)));

static __device__ __forceinline__ short f2bf(float x) {
    unsigned u = __float_as_uint(x);
    unsigned r = (u + 0x7fffu + ((u >> 16) & 1u)) >> 16;   // RNE
    return (short)r;
}
static __device__ __forceinline__ unsigned cvt_pk(float lo, float hi) {
    unsigned r;
    asm("v_cvt_pk_bf16_f32 %0, %1, %2" : "=v"(r) : "v"(lo), "v"(hi));
    return r;
}
static __device__ __forceinline__ void gload_lds16(const short* g, short* l) {
    __builtin_amdgcn_global_load_lds(
        (const __attribute__((address_space(1))) void*)g,
        (__attribute__((address_space(3))) void*)l, 16, 0, 0);
}

// ---------------------------------------------------------------------------
// Kernel 1: K rows -> L2-normalized bf16, tiled+swizzled layout:
// Kn[bh][kt][r][e ^ ((r&7)<<3)] = Khat[bh][kt*64+r][e]
// ---------------------------------------------------------------------------
__global__ __launch_bounds__(256) void norm_k(
    const float* __restrict__ K, short* __restrict__ Kn)
{
    const int tid  = threadIdx.x;
    const int lane = tid & 63;
    long long rid = (long long)blockIdx.x * 16 + (tid >> 6) * 4 + (lane >> 4);
    const int c4 = (lane & 15) * 4;

    const float* src = K + rid * DIM;
    float4 v = *(const float4*)(src + c4);
    float ss = v.x * v.x + v.y * v.y + v.z * v.z + v.w * v.w;
    ss += __shfl_xor(ss, 1);
    ss += __shfl_xor(ss, 2);
    ss += __shfl_xor(ss, 4);
    ss += __shfl_xor(ss, 8);
    float s = 1.0f / (sqrtf(ss) + EPS);

    const int bh = (int)(rid >> 11);
    const int n  = (int)(rid & 2047);
    const int kt = n >> 6;
    const int r  = n & 63;
    short* dst = Kn + ((size_t)bh << 17) + (kt << 12) + (r << 6);

    s16x4 o;
    o[0] = f2bf(v.x * s);
    o[1] = f2bf(v.y * s);
    o[2] = f2bf(v.z * s);
    o[3] = f2bf(v.w * s);
    *(s16x4*)(dst + (c4 ^ ((r & 7) << 3))) = o;
}

// ---------------------------------------------------------------------------
// Kernel 2: V [n][d] fp32 -> Vt tiled+swizzled bf16:
// Vt[bh][kt][d][k ^ ((d&7)<<3)] = V[bh][kt*64+k][d]
// ---------------------------------------------------------------------------
#define TLDS 68

__global__ __launch_bounds__(256) void transpose_v(
    const float* __restrict__ V, short* __restrict__ Vt)
{
    const int nt = blockIdx.x;
    const int bh = blockIdx.y;
    const float* Vb = V + ((size_t)bh * SEQ + (size_t)nt * 64) * DIM;
    short* Vo = Vt + ((size_t)bh << 17) + (nt << 12);

    __shared__ short lds[DIM * TLDS];
    const int t  = threadIdx.x;
    const int cg = t & 15;
    const int rr = t >> 4;

#pragma unroll
    for (int i = 0; i < 4; ++i) {
        int n  = rr + i * 16;
        int d0 = cg * 4;
        float4 v = *(const float4*)(Vb + (size_t)n * DIM + d0);
        lds[(d0 + 0) * TLDS + n] = f2bf(v.x);
        lds[(d0 + 1) * TLDS + n] = f2bf(v.y);
        lds[(d0 + 2) * TLDS + n] = f2bf(v.z);
        lds[(d0 + 3) * TLDS + n] = f2bf(v.w);
    }
    __syncthreads();
#pragma unroll
    for (int i = 0; i < 4; ++i) {
        int d  = rr + i * 16;
        int nl = cg * 4;
        s16x4 o;
        o[0] = lds[d * TLDS + nl + 0];
        o[1] = lds[d * TLDS + nl + 1];
        o[2] = lds[d * TLDS + nl + 2];
        o[3] = lds[d * TLDS + nl + 3];
        *(s16x4*)(Vo + (d << 6) + (nl ^ ((d & 7) << 3))) = o;
    }
}

// ---------------------------------------------------------------------------
// Kernel 3: flash attention. 512 threads = 8 waves, QBLK=256, rounds of
// 128 keys (two 64-tiles). Grid 512 = 2 blocks/CU, pair-balanced (18
// rounds per CU exactly). Double-buffered 32 KB stages, counted vmcnt.
//
// mfma_f32_32x32x16_bf16 layouts:
//   A: row = lane&31, k = (lane>>5)*8 + j
//   B: col = lane&31, k = (lane>>5)*8 + j
//   C/D: col = lane&31, row = (reg&3) + 8*(reg>>2) + 4*(lane>>5)
// ---------------------------------------------------------------------------
__global__ __launch_bounds__(512) void attn_fwd(
    const float* __restrict__ Q, const float* __restrict__ scale,
    const short* __restrict__ Kn, const short* __restrict__ Vt,
    float* __restrict__ out)
{
    const int lid = blockIdx.x;                       // 0..511
    // co-resident pair {lid, lid+256}: qb sums to 7 -> 18 rounds per CU
    const int q2  = lid >> 6;                         // 0..7
    const int qb  = (lid < 256) ? (7 - q2) : (q2 - 4);
    const int bh  = (lid & 7) * 8 + ((lid >> 3) & 7); // XCD lid%8 owns bh/8
    const int tid = threadIdx.x;
    const int w   = tid >> 6;                         // wave 0..7
    const int l   = tid & 63;
    const int lq  = l & 31;
    const int hi  = l >> 5;

    const short* Kb = Kn + ((size_t)bh << 17);
    const short* Vb = Vt + ((size_t)bh << 17);
    const float  g  = scale[bh & (HEADS - 1)];

    __shared__ __align__(16) short ldsK[2][128 * 64];
    __shared__ __align__(16) short ldsV[2][128 * 64];

    const int toff = tid * 8;   // 512 thr x 8 shorts = 4096 shorts per gload

    const int wlo  = qb * 256 + w * 32;   // wave's first q-row
    const int whi  = wlo + 31;
    const int qrow = wlo + lq;
    const int nr   = 2 * qb + 2;          // 128-key rounds

    // ---- Q loads FIRST (oldest in vmcnt queue; their use-wait drains them
    //      before the steady loop, leaving only stage loads outstanding) ----
    const float* Qrow = Q + ((size_t)bh * SEQ + qrow) * DIM;
    float qv[4][8];
#pragma unroll
    for (int c = 0; c < 4; ++c) {
        float4 a = *(const float4*)(Qrow + c * 16 + hi * 8);
        float4 b = *(const float4*)(Qrow + c * 16 + hi * 8 + 4);
        qv[c][0] = a.x; qv[c][1] = a.y; qv[c][2] = a.z; qv[c][3] = a.w;
        qv[c][4] = b.x; qv[c][5] = b.y; qv[c][6] = b.z; qv[c][7] = b.w;
    }

    // ---- prologue: stage round 0 (two 64-tiles = 16 KB K + 16 KB V) ----
    gload_lds16(Kb + toff,        &ldsK[0][toff]);
    gload_lds16(Kb + 4096 + toff, &ldsK[0][4096 + toff]);
    gload_lds16(Vb + toff,        &ldsV[0][toff]);
    gload_lds16(Vb + 4096 + toff, &ldsV[0][4096 + toff]);

    // ---- fused Q-norm (overlaps stage-0 latency) ----
    float ss = 0.f;
#pragma unroll
    for (int c = 0; c < 4; ++c)
#pragma unroll
        for (int jj = 0; jj < 8; ++jj) ss += qv[c][jj] * qv[c][jj];
    ss += __shfl_xor(ss, 32);
    const float sc = g * LOG2E / (sqrtf(ss) + EPS);

    bf16x8 qbf[4];
#pragma unroll
    for (int c = 0; c < 4; ++c) {
        u32x4 wds;
#pragma unroll
        for (int m = 0; m < 4; ++m)
            wds[m] = cvt_pk(qv[c][2 * m] * sc, qv[c][2 * m + 1] * sc);
        qbf[c] = __builtin_bit_cast(bf16x8, wds);
    }

    fx16 oacc[2];
#pragma unroll
    for (int dt = 0; dt < 2; ++dt)
#pragma unroll
        for (int r = 0; r < 16; ++r) oacc[dt][r] = 0.f;
    float lsum = 0.f;

    int cur = 0;
    for (int rr = 0; rr < nr; ++rr) {
        // bar A: all waves finished compute(rr-1) -> buf[cur^1] free
        __builtin_amdgcn_s_barrier();

        if (rr + 1 < nr) {
            const int nb = cur ^ 1;
            const short* gK = Kb + (size_t)(rr + 1) * 8192;
            const short* gV = Vb + (size_t)(rr + 1) * 8192;
            gload_lds16(gK + toff,        &ldsK[nb][toff]);
            gload_lds16(gK + 4096 + toff, &ldsK[nb][4096 + toff]);
            gload_lds16(gV + toff,        &ldsV[nb][toff]);
            gload_lds16(gV + 4096 + toff, &ldsV[nb][4096 + toff]);
            // own stage(rr) done; stage(rr+1)'s 4 loads stay in flight
            asm volatile("s_waitcnt vmcnt(4)" ::: "memory");
        } else {
            asm volatile("s_waitcnt vmcnt(0)" ::: "memory");
        }
        // bar B: all waves' stage(rr) slices visible
        __builtin_amdgcn_s_barrier();

        // ---- two 64-key sub-tiles, back-to-back (independent chains) ----
#pragma unroll
        for (int s = 0; s < 2; ++s) {
            const int k0 = rr * 128 + s * 64;
            if (k0 > whi) continue;   // wave-uniform skip, barriers outside
            const short* lk = &ldsK[cur][s * 4096];
            const short* lv = &ldsV[cur][s * 4096];

            fx16 sacc[2];
#pragma unroll
            for (int t = 0; t < 2; ++t)
#pragma unroll
                for (int r = 0; r < 16; ++r) sacc[t][r] = 0.f;

            bf16x8 kf[2][4];
#pragma unroll
            for (int t = 0; t < 2; ++t)
#pragma unroll
                for (int c = 0; c < 4; ++c) {
                    int r = t * 32 + lq;
                    kf[t][c] = *(const bf16x8*)
                        &lk[(r << 6) + ((c * 16 + hi * 8) ^ ((r & 7) << 3))];
                }
            __builtin_amdgcn_s_setprio(1);
#pragma unroll
            for (int c = 0; c < 4; ++c) {
                sacc[0] = __builtin_amdgcn_mfma_f32_32x32x16_bf16(kf[0][c], qbf[c], sacc[0], 0, 0, 0);
                sacc[1] = __builtin_amdgcn_mfma_f32_32x32x16_bf16(kf[1][c], qbf[c], sacc[1], 0, 0, 0);
            }
            __builtin_amdgcn_s_setprio(0);

            bf16x8 vf[2][4];
#pragma unroll
            for (int dt = 0; dt < 2; ++dt)
#pragma unroll
                for (int ks = 0; ks < 4; ++ks) {
                    int d = dt * 32 + lq;
                    vf[dt][ks] = *(const bf16x8*)
                        &lv[(d << 6) + ((ks * 16 + hi * 8) ^ ((d & 7) << 3))];
                }

            float pv[32];
#pragma unroll
            for (int t = 0; t < 2; ++t)
#pragma unroll
                for (int r = 0; r < 16; ++r) pv[t * 16 + r] = sacc[t][r];

            // causal mask: only the wave's diagonal sub-tile
            if (k0 + 63 > wlo) {
#pragma unroll
                for (int t = 0; t < 2; ++t)
#pragma unroll
                    for (int r = 0; r < 16; ++r) {
                        int key = k0 + 32 * t + (r & 3) + 8 * (r >> 2) + 4 * hi;
                        if (key > qrow) pv[t * 16 + r] = -3.0e38f;
                    }
            }

            // p = exp2(s): cosine-bounded scores, no max shift needed
#pragma unroll
            for (int r = 0; r < 32; ++r)
                pv[r] = __builtin_amdgcn_exp2f(pv[r]);

            // lsum += row sum
            float ts[16];
#pragma unroll
            for (int r = 0; r < 16; ++r) ts[r] = pv[r] + pv[r + 16];
#pragma unroll
            for (int r = 0; r < 8; ++r) ts[r] += ts[r + 8];
#pragma unroll
            for (int r = 0; r < 4; ++r) ts[r] += ts[r + 4];
            float ps = (ts[0] + ts[1]) + (ts[2] + ts[3]);
            ps += __shfl_xor(ps, 32);
            lsum += ps;

            // repack P -> B-fragments via v_permlane32_swap_b32
            u32x4 paw[4];
#pragma unroll
            for (int ks = 0; ks < 4; ++ks) {
                const int t = ks >> 1;
                const int b0 = (ks & 1) * 8;
#pragma unroll
                for (int m = 0; m < 2; ++m) {
                    unsigned a = cvt_pk(pv[t * 16 + b0 + 2 * m], pv[t * 16 + b0 + 2 * m + 1]);
                    unsigned b = cvt_pk(pv[t * 16 + b0 + 2 * m + 4], pv[t * 16 + b0 + 2 * m + 5]);
                    asm("v_permlane32_swap_b32 %0, %1" : "+v"(a), "+v"(b));
                    paw[ks][m]     = a;
                    paw[ks][m + 2] = b;
                }
            }

            // O' += Vt x P
            __builtin_amdgcn_s_setprio(1);
#pragma unroll
            for (int dt = 0; dt < 2; ++dt)
#pragma unroll
                for (int ks = 0; ks < 4; ++ks) {
                    bf16x8 pa = __builtin_bit_cast(bf16x8, paw[ks]);
                    oacc[dt] = __builtin_amdgcn_mfma_f32_32x32x16_bf16(vf[dt][ks], pa, oacc[dt], 0, 0, 0);
                }
            __builtin_amdgcn_s_setprio(0);
        }
        cur ^= 1;
    }

    // ---- epilogue: out[q][d] = O'/lsum ----
    float inv = 1.0f / lsum;
    size_t rb = ((size_t)bh * SEQ + (size_t)qrow) * DIM;
#pragma unroll
    for (int dt = 0; dt < 2; ++dt)
#pragma unroll
        for (int g4 = 0; g4 < 4; ++g4) {
            float4 o4;
            o4.x = oacc[dt][4 * g4 + 0] * inv;
            o4.y = oacc[dt][4 * g4 + 1] * inv;
            o4.z = oacc[dt][4 * g4 + 2] * inv;
            o4.w = oacc[dt][4 * g4 + 3] * inv;
            *(float4*)(out + rb + dt * 32 + 8 * g4 + 4 * hi) = o4;
        }
}

// ---------------------------------------------------------------------------
extern "C" void kernel_launch(void* const* d_in, const int* in_sizes, int n_in,
                              void* d_out, int out_size, void* d_ws, size_t ws_size,
                              hipStream_t stream)
{
    const float* Q  = (const float*)d_in[0];
    const float* K  = (const float*)d_in[1];
    const float* V  = (const float*)d_in[2];
    const float* qs = (const float*)d_in[3];
    float* out = (float*)d_out;

    const size_t nElem = (size_t)BATCH * HEADS * SEQ * DIM;
    short* Kn = (short*)d_ws;
    short* Vt = Kn + nElem;

    {
        long long rows = (long long)BATCH * HEADS * SEQ;
        norm_k<<<(int)(rows / 16), 256, 0, stream>>>(K, Kn);
    }
    {
        dim3 grid(SEQ / 64, BATCH * HEADS);
        transpose_v<<<grid, 256, 0, stream>>>(V, Vt);
    }
    {
        // 512 blocks = 2/CU, pair-balanced to 18 rounds per CU
        attn_fwd<<<(SEQ / 256) * BATCH * HEADS, 512, 0, stream>>>(Q, qs, Kn, Vt, out);
    }
}